// Round 6
// baseline (89.662 us; speedup 1.0000x reference)
//
#include <hip/hip_runtime.h>
#include <stdint.h>
#include <stddef.h>

#define DD   256
#define CC   8
#define BB   16
#define RPB  64           // rows per block
#define NBLK 512          // 32768 / 64
#define KPB  32           // NBLK / BB
#define XROW 264          // padded LDS row stride (words) — pad BETWEEN rows only

// global_load_lds: per-lane global src (16B), wave-uniform LDS base (+lane*16B)
#define GLOAD16(g, l) __builtin_amdgcn_global_load_lds(                      \
    (const __attribute__((address_space(1))) void*)(g),                      \
    (__attribute__((address_space(3))) void*)(l), 16, 0, 0)

__device__ __forceinline__ float dot4(float4 a, float4 b) {
  return a.x * b.x + a.y * b.y + a.z * b.z + a.w * b.w;
}

__global__ __launch_bounds__(256) void lde_main(
    const float* __restrict__ x,        // [32768, 256]
    const float* __restrict__ centers,  // [8, 256]
    const float* __restrict__ scale,    // [8]
    float* __restrict__ pa,             // ws: [C][NBLK][D] partials of sum a*x
    float* __restrict__ pas)            // ws: [C][NBLK]    partials of sum a
{
  __shared__ __align__(16) float x_lds[RPB * XROW];  // 66 KB (reused for reduce)
  __shared__ __align__(16) float c_lds[CC * DD];     // 8 KB
  __shared__ __align__(16) float a_lds[RPB * CC];    // 2 KB

  const int tid  = threadIdx.x;
  const int lane = tid & 63;
  const int wave = tid >> 6;
  const int blk  = blockIdx.x;

  // ---- centers global loads FIRST (oldest in vmcnt order) ----
  const float4 cg0 = ((const float4*)centers)[tid];
  const float4 cg1 = ((const float4*)centers)[tid + 256];
  __builtin_amdgcn_sched_barrier(0);

  // ---- issue 16 direct-to-LDS x row loads (own wave's rows only) ----
  const int  lrow0 = wave * 16;
  const long grow0 = (long)blk * RPB + lrow0;
  #pragma unroll
  for (int r = 0; r < 16; ++r)
    GLOAD16(x + (grow0 + r) * DD + lane * 4, &x_lds[(lrow0 + r) * XROW]);
  __builtin_amdgcn_sched_barrier(0);

  // ---- c_lds write (waits only the 2 centers loads: vmcnt(16)) ----
  ((float4*)c_lds)[tid]       = cg0;
  ((float4*)c_lds)[tid + 256] = cg1;

  float sv[CC];
  #pragma unroll
  for (int c = 0; c < CC; ++c) sv[c] = scale[c];   // uniform -> s_loads

  // rendezvous WITHOUT vmcnt drain: only LDS writes must be visible
  asm volatile("s_waitcnt lgkmcnt(0)" ::: "memory");
  __builtin_amdgcn_s_barrier();
  __builtin_amdgcn_sched_barrier(0);

  // ---- csq[c] = ||centers[c]||^2 (per-wave redundant; DS+VALU under HBM) ----
  float csqv[CC];
  {
    const int c = lane >> 3, oo = lane & 7;
    float cs = 0.f;
    #pragma unroll
    for (int k = 0; k < 8; ++k) {
      const float4 cv = *(const float4*)&c_lds[c * DD + k * 32 + oo * 4];
      cs += dot4(cv, cv);
    }
    cs += __shfl_xor(cs, 1);
    cs += __shfl_xor(cs, 2);
    cs += __shfl_xor(cs, 4);
    #pragma unroll
    for (int cc = 0; cc < CC; ++cc) csqv[cc] = __shfl(cs, cc * 8);
  }

  const int o  = lane & 7;    // d-octant
  const int rl = lane >> 3;   // row within half
  float4 acc[CC];
  #pragma unroll
  for (int c = 0; c < CC; ++c) acc[c] = make_float4(0.f, 0.f, 0.f, 0.f);

  // ================= two software-pipelined halves =================
  #pragma unroll
  for (int h = 0; h < 2; ++h) {
    if (h == 0) { asm volatile("s_waitcnt vmcnt(8)" ::: "memory"); }
    else        { asm volatile("s_waitcnt vmcnt(0)" ::: "memory"); }
    __builtin_amdgcn_sched_barrier(0);

    // ---- phase 1: assignment for rows [wave*16 + h*8 + rl] (1 row/lane) ----
    {
      const int  row = lrow0 + h * 8 + rl;
      const float* xr = &x_lds[row * XROW];
      float dots[CC] = {0,0,0,0,0,0,0,0};
      float xsq = 0.f;
      #pragma unroll
      for (int k = 0; k < 8; ++k) {
        const float4 xv = *(const float4*)&xr[k * 32 + o * 4];
        xsq += dot4(xv, xv);
        #pragma unroll
        for (int c = 0; c < CC; ++c) {
          const float4 cv = *(const float4*)&c_lds[c * DD + k * 32 + o * 4];
          dots[c] += dot4(xv, cv);
        }
      }
      xsq += __shfl_xor(xsq, 1); xsq += __shfl_xor(xsq, 2); xsq += __shfl_xor(xsq, 4);
      #pragma unroll
      for (int c = 0; c < CC; ++c) {
        dots[c] += __shfl_xor(dots[c], 1);
        dots[c] += __shfl_xor(dots[c], 2);
        dots[c] += __shfl_xor(dots[c], 4);
      }
      float lgt[CC], m = -1e30f;
      #pragma unroll
      for (int c = 0; c < CC; ++c) {
        lgt[c] = -sv[c] * (xsq - 2.f * dots[c] + csqv[c]);
        m = fmaxf(m, lgt[c]);
      }
      float e[CC], ssum = 0.f;
      #pragma unroll
      for (int c = 0; c < CC; ++c) { e[c] = __expf(lgt[c] - m); ssum += e[c]; }
      const float inv = 1.f / ssum;
      const float eo = (o == 0) ? e[0] : (o == 1) ? e[1] : (o == 2) ? e[2] : (o == 3) ? e[3]
                     : (o == 4) ? e[4] : (o == 5) ? e[5] : (o == 6) ? e[6] : e[7];
      a_lds[row * CC + o] = eo * inv;   // bank = lane -> conflict-free
    }

    // ---- phase 2: accumulate these 8 rows; a via uniform-addr broadcast ----
    #pragma unroll
    for (int r = 0; r < 8; ++r) {
      const int  row = lrow0 + h * 8 + r;
      const float4 xv = *(const float4*)&x_lds[row * XROW + lane * 4];
      const float4 a0 = *(const float4*)&a_lds[row * CC];       // broadcast
      const float4 a1 = *(const float4*)&a_lds[row * CC + 4];   // broadcast
      acc[0].x += a0.x * xv.x; acc[0].y += a0.x * xv.y; acc[0].z += a0.x * xv.z; acc[0].w += a0.x * xv.w;
      acc[1].x += a0.y * xv.x; acc[1].y += a0.y * xv.y; acc[1].z += a0.y * xv.z; acc[1].w += a0.y * xv.w;
      acc[2].x += a0.z * xv.x; acc[2].y += a0.z * xv.y; acc[2].z += a0.z * xv.z; acc[2].w += a0.z * xv.w;
      acc[3].x += a0.w * xv.x; acc[3].y += a0.w * xv.y; acc[3].z += a0.w * xv.z; acc[3].w += a0.w * xv.w;
      acc[4].x += a1.x * xv.x; acc[4].y += a1.x * xv.y; acc[4].z += a1.x * xv.z; acc[4].w += a1.x * xv.w;
      acc[5].x += a1.y * xv.x; acc[5].y += a1.y * xv.y; acc[5].z += a1.y * xv.z; acc[5].w += a1.y * xv.w;
      acc[6].x += a1.z * xv.x; acc[6].y += a1.z * xv.y; acc[6].z += a1.z * xv.z; acc[6].w += a1.z * xv.w;
      acc[7].x += a1.w * xv.x; acc[7].y += a1.w * xv.y; acc[7].z += a1.w * xv.z; acc[7].w += a1.w * xv.w;
    }
  }

  __syncthreads();   // all waves done with their x_lds rows

  // ---- cross-wave reduce (reuse x_lds as [4][C][D]) + partial store ----
  float* p_lds = x_lds;
  #pragma unroll
  for (int c = 0; c < CC; ++c)
    *(float4*)&p_lds[(wave * CC + c) * DD + lane * 4] = acc[c];
  __syncthreads();

  if (wave == 0) {   // pas partial: a_lds has all 64 rows
    const int c = lane >> 3, oo = lane & 7;
    float s = 0.f;
    #pragma unroll
    for (int j = 0; j < 8; ++j) s += a_lds[(j * 8 + oo) * CC + c];
    s += __shfl_xor(s, 1);
    s += __shfl_xor(s, 2);
    s += __shfl_xor(s, 4);
    if (oo == 0) pas[c * NBLK + blk] = s;
  }

  {
    const int c = tid >> 5;              // 0..7
    const int g = tid & 31;
    #pragma unroll
    for (int hh = 0; hh < 2; ++hh) {
      const int d4 = g + 32 * hh;
      const float4 s0 = *(const float4*)&p_lds[(0 * CC + c) * DD + d4 * 4];
      const float4 s1 = *(const float4*)&p_lds[(1 * CC + c) * DD + d4 * 4];
      const float4 s2 = *(const float4*)&p_lds[(2 * CC + c) * DD + d4 * 4];
      const float4 s3 = *(const float4*)&p_lds[(3 * CC + c) * DD + d4 * 4];
      const float4 s = make_float4(s0.x + s1.x + s2.x + s3.x, s0.y + s1.y + s2.y + s3.y,
                                   s0.z + s1.z + s2.z + s3.z, s0.w + s1.w + s2.w + s3.w);
      *(float4*)&pa[((size_t)c * NBLK + blk) * DD + d4 * 4] = s;
    }
  }
}

// out[b,c,d] = sum_k pa[c][b*32+k][d] - (sum_k pas[c][b*32+k]) * centers[c][d]
__global__ __launch_bounds__(256) void lde_finalize(
    const float* __restrict__ pa,
    const float* __restrict__ pas,
    const float* __restrict__ centers,
    float* __restrict__ out)
{
  __shared__ __align__(16) float r_lds[4][DD];
  const int b  = blockIdx.x >> 3;
  const int c  = blockIdx.x & 7;
  const int kq = threadIdx.x >> 6;     // wave id 0..3
  const int d4 = threadIdx.x & 63;     // float4 index over D

  const float* base = pa + ((size_t)c * NBLK + b * KPB) * DD;
  float4 s = make_float4(0.f, 0.f, 0.f, 0.f);
  #pragma unroll
  for (int j = 0; j < 8; ++j) {
    const float4 v = *(const float4*)&base[(kq * 8 + j) * DD + d4 * 4];
    s.x += v.x; s.y += v.y; s.z += v.z; s.w += v.w;
  }
  *(float4*)&r_lds[kq][d4 * 4] = s;
  __syncthreads();

  if (kq == 0) {
    const float4 t0 = *(const float4*)&r_lds[0][d4 * 4];
    const float4 t1 = *(const float4*)&r_lds[1][d4 * 4];
    const float4 t2 = *(const float4*)&r_lds[2][d4 * 4];
    const float4 t3 = *(const float4*)&r_lds[3][d4 * 4];
    const float4 t = make_float4(t0.x + t1.x + t2.x + t3.x, t0.y + t1.y + t2.y + t3.y,
                                 t0.z + t1.z + t2.z + t3.z, t0.w + t1.w + t2.w + t3.w);
    float v = pas[c * NBLK + b * KPB + (d4 & 31)];
    v += __shfl_xor(v, 1); v += __shfl_xor(v, 2); v += __shfl_xor(v, 4);
    v += __shfl_xor(v, 8); v += __shfl_xor(v, 16);
    const float4 cv = *(const float4*)&centers[c * DD + d4 * 4];
    *(float4*)&out[(size_t)(b * CC + c) * DD + d4 * 4] =
        make_float4(t.x - v * cv.x, t.y - v * cv.y, t.z - v * cv.z, t.w - v * cv.w);
  }
}

extern "C" void kernel_launch(void* const* d_in, const int* in_sizes, int n_in,
                              void* d_out, int out_size, void* d_ws, size_t ws_size,
                              hipStream_t stream)
{
  const float* x       = (const float*)d_in[0];
  const float* centers = (const float*)d_in[1];
  const float* scale   = (const float*)d_in[2];
  float* out = (float*)d_out;

  float* pa  = (float*)d_ws;                       // 8*512*256*4 = 4 MB
  float* pas = pa + (size_t)CC * NBLK * DD;        // 16 KB

  lde_main<<<NBLK, 256, 0, stream>>>(x, centers, scale, pa, pas);
  lde_finalize<<<BB * CC, 256, 0, stream>>>(pa, pas, centers, out);
}

// Round 7
// 83.567 us; speedup vs baseline: 1.0729x; 1.0729x over previous
//
#include <hip/hip_runtime.h>
#include <stdint.h>
#include <stddef.h>

#define DD   256
#define CC   8
#define BB   16
#define RPB  64           // rows per block
#define NBLK 512          // 32768 / 64
#define KPB  32           // NBLK / BB  = partial sets per batch image
#define XROW 264          // padded LDS row stride (words)

// global_load_lds: per-lane global src (16B), wave-uniform LDS base (+lane*16B)
#define GLOAD16(g, l) __builtin_amdgcn_global_load_lds(                      \
    (const __attribute__((address_space(1))) void*)(g),                      \
    (__attribute__((address_space(3))) void*)(l), 16, 0, 0)

__device__ __forceinline__ float dot4(float4 a, float4 b) {
  return a.x * b.x + a.y * b.y + a.z * b.z + a.w * b.w;
}

__global__ __launch_bounds__(256) void lde_main(
    const float* __restrict__ x,        // [32768, 256]
    const float* __restrict__ centers,  // [8, 256]
    const float* __restrict__ scale,    // [8]
    float* __restrict__ pa,             // ws: [C][NBLK][D] block partials of sum a*x
    float* __restrict__ pas)            // ws: [C][NBLK]    block partials of sum a
{
  __shared__ __align__(16) float x_lds[RPB * XROW];  // 66 KB padded rows (reused for reduce)
  __shared__ __align__(16) float c_lds[CC * DD];     // 8 KB
  __shared__ __align__(16) float a_lds[RPB * CC];    // 2 KB

  const int tid  = threadIdx.x;
  const int lane = tid & 63;
  const int wave = tid >> 6;
  const int blk  = blockIdx.x;

  float sv[CC];
  #pragma unroll
  for (int c = 0; c < CC; ++c) sv[c] = scale[c];   // uniform -> scalar loads

  // ---- stage x tile: wave issues 16 direct-to-LDS row loads (1 KB each) ----
  {
    const int  lrow0 = wave * 16;
    const long grow0 = (long)blk * RPB + lrow0;
    #pragma unroll
    for (int r = 0; r < 16; ++r) {
      const float* g = x + (grow0 + r) * DD + lane * 4;
      GLOAD16(g, &x_lds[(lrow0 + r) * XROW]);
    }
  }
  // ---- stage centers ----
  {
    const float4* cg = (const float4*)centers;
    float4* cl = (float4*)c_lds;
    cl[tid]       = cg[tid];
    cl[tid + 256] = cg[tid + 256];
  }
  asm volatile("s_waitcnt vmcnt(0)" ::: "memory");
  __syncthreads();

  // ---- csq[c] = ||centers[c]||^2 : lane (c=lane>>3, oo=lane&7), octet butterfly ----
  float csqv[CC];
  {
    const int c = lane >> 3, oo = lane & 7;
    float cs = 0.f;
    #pragma unroll
    for (int k = 0; k < 8; ++k) {
      float4 cv = *(const float4*)&c_lds[c * DD + k * 32 + oo * 4];
      cs += dot4(cv, cv);
    }
    cs += __shfl_xor(cs, 1);
    cs += __shfl_xor(cs, 2);
    cs += __shfl_xor(cs, 4);
    #pragma unroll
    for (int cc = 0; cc < CC; ++cc) csqv[cc] = __shfl(cs, cc * 8);
  }

  // ---- Phase 1: 8 lanes/row, 2 rows/lane (each c-chunk read feeds 2 rows) ----
  {
    const int o  = lane & 7;
    const int rl = lane >> 3;
    const int r0 = wave * 16 + rl;      // rows r0 and r0+8
    const float* xr0 = &x_lds[r0 * XROW];
    const float* xr1 = &x_lds[(r0 + 8) * XROW];

    float d0[CC] = {0,0,0,0,0,0,0,0};
    float d1[CC] = {0,0,0,0,0,0,0,0};
    float xq0 = 0.f, xq1 = 0.f;
    #pragma unroll
    for (int k = 0; k < 8; ++k) {
      const float4 xv0 = *(const float4*)&xr0[k * 32 + o * 4];
      const float4 xv1 = *(const float4*)&xr1[k * 32 + o * 4];
      xq0 += dot4(xv0, xv0);
      xq1 += dot4(xv1, xv1);
      #pragma unroll
      for (int c = 0; c < CC; ++c) {
        const float4 cv = *(const float4*)&c_lds[c * DD + k * 32 + o * 4];
        d0[c] += dot4(xv0, cv);
        d1[c] += dot4(xv1, cv);
      }
    }
    xq0 += __shfl_xor(xq0, 1); xq0 += __shfl_xor(xq0, 2); xq0 += __shfl_xor(xq0, 4);
    xq1 += __shfl_xor(xq1, 1); xq1 += __shfl_xor(xq1, 2); xq1 += __shfl_xor(xq1, 4);
    #pragma unroll
    for (int c = 0; c < CC; ++c) {
      d0[c] += __shfl_xor(d0[c], 1); d0[c] += __shfl_xor(d0[c], 2); d0[c] += __shfl_xor(d0[c], 4);
      d1[c] += __shfl_xor(d1[c], 1); d1[c] += __shfl_xor(d1[c], 2); d1[c] += __shfl_xor(d1[c], 4);
    }

    // softmax row r0
    {
      float lgt[CC], m = -1e30f;
      #pragma unroll
      for (int c = 0; c < CC; ++c) { lgt[c] = -sv[c] * (xq0 - 2.f * d0[c] + csqv[c]); m = fmaxf(m, lgt[c]); }
      float e[CC], ssum = 0.f;
      #pragma unroll
      for (int c = 0; c < CC; ++c) { e[c] = __expf(lgt[c] - m); ssum += e[c]; }
      const float inv = 1.f / ssum;
      float eo = (o == 0) ? e[0] : (o == 1) ? e[1] : (o == 2) ? e[2] : (o == 3) ? e[3]
               : (o == 4) ? e[4] : (o == 5) ? e[5] : (o == 6) ? e[6] : e[7];
      a_lds[r0 * CC + o] = eo * inv;
    }
    // softmax row r0+8
    {
      float lgt[CC], m = -1e30f;
      #pragma unroll
      for (int c = 0; c < CC; ++c) { lgt[c] = -sv[c] * (xq1 - 2.f * d1[c] + csqv[c]); m = fmaxf(m, lgt[c]); }
      float e[CC], ssum = 0.f;
      #pragma unroll
      for (int c = 0; c < CC; ++c) { e[c] = __expf(lgt[c] - m); ssum += e[c]; }
      const float inv = 1.f / ssum;
      float eo = (o == 0) ? e[0] : (o == 1) ? e[1] : (o == 2) ? e[2] : (o == 3) ? e[3]
               : (o == 4) ? e[4] : (o == 5) ? e[5] : (o == 6) ? e[6] : e[7];
      a_lds[(r0 + 8) * CC + o] = eo * inv;
    }
  }
  __syncthreads();

  // ---- pas block partial (wave 0 only) ----
  if (wave == 0) {
    const int c = lane >> 3, oo = lane & 7;
    float s = 0.f;
    #pragma unroll
    for (int j = 0; j < 8; ++j) s += a_lds[(j * 8 + oo) * CC + c];
    s += __shfl_xor(s, 1);
    s += __shfl_xor(s, 2);
    s += __shfl_xor(s, 4);
    if (oo == 0) pas[c * NBLK + blk] = s;
  }

  // ---- Phase 2: wave w rows w*16..+15, lane owns float4 d-chunk;
  //      a via uniform-address ds_read_b128 broadcast (cheaper than shfl) ----
  float4 acc[CC];
  #pragma unroll
  for (int c = 0; c < CC; ++c) acc[c] = make_float4(0.f, 0.f, 0.f, 0.f);
  {
    #pragma unroll
    for (int r = 0; r < 16; ++r) {
      const int  row = wave * 16 + r;
      const float4 xv = *(const float4*)&x_lds[row * XROW + lane * 4];
      const float4 a0 = *(const float4*)&a_lds[row * CC];       // broadcast
      const float4 a1 = *(const float4*)&a_lds[row * CC + 4];   // broadcast
      acc[0].x += a0.x * xv.x; acc[0].y += a0.x * xv.y; acc[0].z += a0.x * xv.z; acc[0].w += a0.x * xv.w;
      acc[1].x += a0.y * xv.x; acc[1].y += a0.y * xv.y; acc[1].z += a0.y * xv.z; acc[1].w += a0.y * xv.w;
      acc[2].x += a0.z * xv.x; acc[2].y += a0.z * xv.y; acc[2].z += a0.z * xv.z; acc[2].w += a0.z * xv.w;
      acc[3].x += a0.w * xv.x; acc[3].y += a0.w * xv.y; acc[3].z += a0.w * xv.z; acc[3].w += a0.w * xv.w;
      acc[4].x += a1.x * xv.x; acc[4].y += a1.x * xv.y; acc[4].z += a1.x * xv.z; acc[4].w += a1.x * xv.w;
      acc[5].x += a1.y * xv.x; acc[5].y += a1.y * xv.y; acc[5].z += a1.y * xv.z; acc[5].w += a1.y * xv.w;
      acc[6].x += a1.z * xv.x; acc[6].y += a1.z * xv.y; acc[6].z += a1.z * xv.z; acc[6].w += a1.z * xv.w;
      acc[7].x += a1.w * xv.x; acc[7].y += a1.w * xv.y; acc[7].z += a1.w * xv.z; acc[7].w += a1.w * xv.w;
    }
  }
  __syncthreads();                       // everyone done reading x_lds

  // ---- cross-wave reduce (reuse x_lds) + global partial store ----
  float* p_lds = x_lds;                  // [4][C][D] floats = 32 KB
  #pragma unroll
  for (int c = 0; c < CC; ++c)
    *(float4*)&p_lds[(wave * CC + c) * DD + lane * 4] = acc[c];
  __syncthreads();
  {
    const int c = tid >> 5;              // 0..7
    const int g = tid & 31;
    #pragma unroll
    for (int h = 0; h < 2; ++h) {
      const int d4 = g + 32 * h;
      float4 s0 = *(const float4*)&p_lds[(0 * CC + c) * DD + d4 * 4];
      float4 s1 = *(const float4*)&p_lds[(1 * CC + c) * DD + d4 * 4];
      float4 s2 = *(const float4*)&p_lds[(2 * CC + c) * DD + d4 * 4];
      float4 s3 = *(const float4*)&p_lds[(3 * CC + c) * DD + d4 * 4];
      float4 s = make_float4(s0.x + s1.x + s2.x + s3.x, s0.y + s1.y + s2.y + s3.y,
                             s0.z + s1.z + s2.z + s3.z, s0.w + s1.w + s2.w + s3.w);
      *(float4*)&pa[((size_t)c * NBLK + blk) * DD + d4 * 4] = s;
    }
  }
}

// out[b,c,d] = sum_k pa[c][b*32+k][d] - (sum_k pas[c][b*32+k]) * centers[c][d]
__global__ __launch_bounds__(256) void lde_finalize(
    const float* __restrict__ pa,
    const float* __restrict__ pas,
    const float* __restrict__ centers,
    float* __restrict__ out)
{
  __shared__ __align__(16) float r_lds[4][DD];   // 4 KB
  const int b  = blockIdx.x >> 3;
  const int c  = blockIdx.x & 7;
  const int kq = threadIdx.x >> 6;     // 0..3 (wave id)
  const int d4 = threadIdx.x & 63;     // float4 index over D

  const float* base = pa + ((size_t)c * NBLK + b * KPB) * DD;
  float4 s = make_float4(0.f, 0.f, 0.f, 0.f);
  #pragma unroll
  for (int j = 0; j < 8; ++j) {
    const float4 v = *(const float4*)&base[(kq * 8 + j) * DD + d4 * 4];
    s.x += v.x; s.y += v.y; s.z += v.z; s.w += v.w;
  }
  *(float4*)&r_lds[kq][d4 * 4] = s;
  __syncthreads();

  if (kq == 0) {   // wave 0 finishes
    float4 t0 = *(const float4*)&r_lds[0][d4 * 4];
    float4 t1 = *(const float4*)&r_lds[1][d4 * 4];
    float4 t2 = *(const float4*)&r_lds[2][d4 * 4];
    float4 t3 = *(const float4*)&r_lds[3][d4 * 4];
    float4 t = make_float4(t0.x + t1.x + t2.x + t3.x, t0.y + t1.y + t2.y + t3.y,
                           t0.z + t1.z + t2.z + t3.z, t0.w + t1.w + t2.w + t3.w);
    // a_sum: 32 partials, butterfly within 32-lane halves
    float v = pas[c * NBLK + b * KPB + (d4 & 31)];
    v += __shfl_xor(v, 1); v += __shfl_xor(v, 2); v += __shfl_xor(v, 4);
    v += __shfl_xor(v, 8); v += __shfl_xor(v, 16);
    const float4 cv = *(const float4*)&centers[c * DD + d4 * 4];
    float4 o4 = make_float4(t.x - v * cv.x, t.y - v * cv.y, t.z - v * cv.z, t.w - v * cv.w);
    *(float4*)&out[(size_t)(b * CC + c) * DD + d4 * 4] = o4;
  }
}

extern "C" void kernel_launch(void* const* d_in, const int* in_sizes, int n_in,
                              void* d_out, int out_size, void* d_ws, size_t ws_size,
                              hipStream_t stream)
{
  const float* x       = (const float*)d_in[0];
  const float* centers = (const float*)d_in[1];
  const float* scale   = (const float*)d_in[2];
  float* out = (float*)d_out;

  float* pa  = (float*)d_ws;                       // 8*512*256*4 = 4 MB
  float* pas = pa + (size_t)CC * NBLK * DD;        // 16 KB

  lde_main<<<NBLK, 256, 0, stream>>>(x, centers, scale, pa, pas);
  lde_finalize<<<BB * CC, 256, 0, stream>>>(pa, pas, centers, out);
}